// Round 2
// baseline (69.476 us; speedup 1.0000x reference)
//
#include <hip/hip_runtime.h>
#include <stdint.h>

#define NSTRUCT 8
#define NROWS   1024
#define DD      128

// ---------------------------------------------------------------------------
// Kernel A: build effective weight matrix M[o,p,c] = maskings * hard * W
// where hard = (u < theta), u = jax.random.uniform(key(42), (8,128,128)).
//
// JAX threefry2x32, partitionable path (default in modern JAX):
//   (b1, b2) = threefry2x32(key=(0,42), counts=(hi=0, lo=i))
//   bits32[i] = b1 ^ b2          // _threefry_random_bits_partitionable, 32-bit
//   u = bitcast((bits32 >> 9) | 0x3f800000) - 1.0
// ---------------------------------------------------------------------------

__device__ __forceinline__ uint32_t rotl32(uint32_t x, uint32_t d) {
  return (x << d) | (x >> (32u - d));
}

__global__ __launch_bounds__(256) void build_M(
    const float* __restrict__ maskings,
    const float* __restrict__ theta,
    const float* __restrict__ W,
    float* __restrict__ M) {
  uint32_t i = blockIdx.x * 256u + threadIdx.x;  // 0 .. 131071 (flat o,p,c)

  const uint32_t ks0 = 0u;
  const uint32_t ks1 = 42u;
  const uint32_t ks2 = 0x1BD11BDAu ^ ks0 ^ ks1;

  uint32_t x0 = 0u + ks0;   // counts_hi = 0
  uint32_t x1 = i  + ks1;   // counts_lo = flat index

#define TF_RND(r) { x0 += x1; x1 = rotl32(x1, r); x1 ^= x0; }
  TF_RND(13) TF_RND(15) TF_RND(26) TF_RND(6)
  x0 += ks1; x1 += ks2 + 1u;
  TF_RND(17) TF_RND(29) TF_RND(16) TF_RND(24)
  x0 += ks2; x1 += ks0 + 2u;
  TF_RND(13) TF_RND(15) TF_RND(26) TF_RND(6)
  x0 += ks0; x1 += ks1 + 3u;
  TF_RND(17) TF_RND(29) TF_RND(16) TF_RND(24)
  x0 += ks1; x1 += ks2 + 4u;
  TF_RND(13) TF_RND(15) TF_RND(26) TF_RND(6)
  x0 += ks2; x1 += ks0 + 5u;
#undef TF_RND

  // partitionable 32-bit random bits = out0 ^ out1
  uint32_t bits = x0 ^ x1;
  float u = __uint_as_float((bits >> 9) | 0x3f800000u) - 1.0f;
  M[i] = (u < theta[i]) ? maskings[i] * W[i] : 0.0f;
}

// ---------------------------------------------------------------------------
// Kernel B: x_hat[o,n,c] = sum_p x[n,p] * M[o,p,c]
// Grid: 8 structures x 32 row-tiles (32 rows each) = 256 blocks, 256 threads.
// LDS: full x-tile (32x128 fp32, 16 KB) + M p-chunk (32x128 fp32, 16 KB).
// Each thread: 4 rows x 4 cols register micro-tile.
//   - M read: ds_read_b128 at column-contiguous addr -> conflict-free
//   - x read: same addr across the 32 col-lanes -> LDS broadcast
// ---------------------------------------------------------------------------

__global__ __launch_bounds__(256) void sem_gemm(
    const float* __restrict__ x,
    const float* __restrict__ M,
    float* __restrict__ out) {
  __shared__ float xs[32 * DD];   // 16 KB
  __shared__ float Ms[32 * DD];   // 16 KB

  const int o   = blockIdx.x >> 5;         // structure 0..7
  const int n0  = (blockIdx.x & 31) << 5;  // row tile base
  const int tid = threadIdx.x;
  const int r0  = (tid >> 5) << 2;         // 0,4,...,28
  const int c0  = (tid & 31) << 2;         // 0,4,...,124

  // stage x tile: rows n0..n0+31, contiguous in global
  {
    const float4* src = (const float4*)(x + n0 * DD);
    float4* dst = (float4*)xs;
#pragma unroll
    for (int k = 0; k < 4; ++k) dst[tid + k * 256] = src[tid + k * 256];
  }

  float acc[4][4];
#pragma unroll
  for (int a = 0; a < 4; ++a)
#pragma unroll
    for (int b = 0; b < 4; ++b) acc[a][b] = 0.0f;

  const float4* msrcBase = (const float4*)(M + o * DD * DD);

  for (int p0 = 0; p0 < DD; p0 += 32) {
    __syncthreads();  // previous chunk fully consumed (and xs staged, 1st iter)
    {
      const float4* src = msrcBase + (p0 * DD) / 4;
      float4* dst = (float4*)Ms;
#pragma unroll
      for (int k = 0; k < 4; ++k) dst[tid + k * 256] = src[tid + k * 256];
    }
    __syncthreads();

#pragma unroll 8
    for (int pp = 0; pp < 32; ++pp) {
      float4 b = *(const float4*)&Ms[pp * DD + c0];
      float a0 = xs[(r0 + 0) * DD + p0 + pp];
      float a1 = xs[(r0 + 1) * DD + p0 + pp];
      float a2 = xs[(r0 + 2) * DD + p0 + pp];
      float a3 = xs[(r0 + 3) * DD + p0 + pp];
      acc[0][0] += a0 * b.x; acc[0][1] += a0 * b.y; acc[0][2] += a0 * b.z; acc[0][3] += a0 * b.w;
      acc[1][0] += a1 * b.x; acc[1][1] += a1 * b.y; acc[1][2] += a1 * b.z; acc[1][3] += a1 * b.w;
      acc[2][0] += a2 * b.x; acc[2][1] += a2 * b.y; acc[2][2] += a2 * b.z; acc[2][3] += a2 * b.w;
      acc[3][0] += a3 * b.x; acc[3][1] += a3 * b.y; acc[3][2] += a3 * b.z; acc[3][3] += a3 * b.w;
    }
  }

  float* obase = out + ((size_t)o * NROWS + n0) * DD;
#pragma unroll
  for (int a = 0; a < 4; ++a) {
    float4 v = make_float4(acc[a][0], acc[a][1], acc[a][2], acc[a][3]);
    *(float4*)&obase[(r0 + a) * DD + c0] = v;
  }
}

// ---------------------------------------------------------------------------

extern "C" void kernel_launch(void* const* d_in, const int* in_sizes, int n_in,
                              void* d_out, int out_size, void* d_ws, size_t ws_size,
                              hipStream_t stream) {
  const float* x        = (const float*)d_in[0];
  const float* maskings = (const float*)d_in[1];
  const float* theta    = (const float*)d_in[2];
  const float* W        = (const float*)d_in[3];
  float* out = (float*)d_out;
  float* M   = (float*)d_ws;  // 8*128*128 fp32 = 512 KB scratch

  build_M<<<(NSTRUCT * DD * DD) / 256, 256, 0, stream>>>(maskings, theta, W, M);
  sem_gemm<<<NSTRUCT * (NROWS / 32), 256, 0, stream>>>(x, M, out);
}